// Round 1
// baseline (813.547 us; speedup 1.0000x reference)
//
#include <hip/hip_runtime.h>

typedef unsigned short u16;
typedef unsigned int u32;
typedef __attribute__((ext_vector_type(4))) float f32x4;
typedef __attribute__((ext_vector_type(8))) short bf16x8;

// Problem sizes (fixed)
// B=2, S=2048, D=2048, NH=16, NKV=4, HD=128

__device__ __forceinline__ u16 f2b(float f) {
  u32 u = __builtin_bit_cast(u32, f);
  u = (u + 0x7fffu + ((u >> 16) & 1u)) >> 16;  // RNE
  return (u16)u;
}

__device__ __forceinline__ void gload_lds16(const void* g, void* l) {
  __builtin_amdgcn_global_load_lds((const __attribute__((address_space(1))) u32*)g,
                                   (__attribute__((address_space(3))) u32*)l, 16, 0, 0);
}

// ---------------- fp32 -> bf16 conversion ----------------
__global__ void cvt_bf16(const float* __restrict__ src, u16* __restrict__ dst, int n) {
  int stride = gridDim.x * blockDim.x * 4;
  for (int idx = (blockIdx.x * blockDim.x + threadIdx.x) * 4; idx < n; idx += stride) {
    float4 v = *(const float4*)(src + idx);
    ushort4 o;
    o.x = f2b(v.x); o.y = f2b(v.y); o.z = f2b(v.z); o.w = f2b(v.w);
    *(ushort4*)(dst + idx) = o;
  }
}

// ---------------- GEMM: C[M,N] = A[M,K] * B[N,K]^T (both row-major, bf16 in) ----------------
// m97 structure: 128x128 tile, BK=32, 4 waves each computing a 64x64 quadrant,
// global_load_lds width-16 staging, 16x16x32 bf16 MFMA.
// OUT_MODE: 0 = bf16 row-major, 1 = bf16 transposed-per-batch (for V^T), 2 = fp32 row-major
template<int OUT_MODE>
__global__ __launch_bounds__(256) void gemm_bt(const u16* __restrict__ A, const u16* __restrict__ B,
                                               void* __restrict__ Cout, int M, int N, int Kd) {
  __shared__ u16 sA[128 * 32];
  __shared__ u16 sB[128 * 32];
  const int tid = threadIdx.x;
  const int l = tid & 63, w = tid >> 6;
  const int wr = w >> 1, wc = w & 1;
  const int g = l >> 4, c = l & 15;
  const int tm = blockIdx.y * 128, tn = blockIdx.x * 128;

  f32x4 acc[4][4] = {};

  const int r0 = tid >> 2, cc = (tid & 3) << 3;  // each thread stages 8 bf16 = 16B

  for (int k0 = 0; k0 < Kd; k0 += 32) {
    __syncthreads();  // previous iter's LDS reads complete before overwrite
    {
      const u16* srcA0 = A + (size_t)(tm + r0) * Kd + k0 + cc;
      const u16* srcB0 = B + (size_t)(tn + r0) * Kd + k0 + cc;
      gload_lds16(srcA0, (char*)sA + w * 1024);
      gload_lds16(srcB0, (char*)sB + w * 1024);
      gload_lds16(srcA0 + (size_t)64 * Kd, (char*)sA + 4096 + w * 1024);
      gload_lds16(srcB0 + (size_t)64 * Kd, (char*)sB + 4096 + w * 1024);
    }
    __syncthreads();

    bf16x8 af[4], bfr[4];
#pragma unroll
    for (int m = 0; m < 4; ++m)
      af[m] = *(const bf16x8*)(sA + (wr * 64 + m * 16 + c) * 32 + g * 8);
#pragma unroll
    for (int n = 0; n < 4; ++n)
      bfr[n] = *(const bf16x8*)(sB + (wc * 64 + n * 16 + c) * 32 + g * 8);
#pragma unroll
    for (int m = 0; m < 4; ++m)
#pragma unroll
      for (int n = 0; n < 4; ++n)
        acc[m][n] = __builtin_amdgcn_mfma_f32_16x16x32_bf16(af[m], bfr[n], acc[m][n], 0, 0, 0);
  }

  // C/D layout: col = lane&15, row = (lane>>4)*4 + i   [m89-verified]
#pragma unroll
  for (int m = 0; m < 4; ++m)
#pragma unroll
    for (int n = 0; n < 4; ++n)
#pragma unroll
      for (int i = 0; i < 4; ++i) {
        int row = tm + wr * 64 + m * 16 + g * 4 + i;
        int col = tn + wc * 64 + n * 16 + c;
        float v = acc[m][n][i];
        if constexpr (OUT_MODE == 2) {
          ((float*)Cout)[(size_t)row * N + col] = v;
        } else if constexpr (OUT_MODE == 0) {
          ((u16*)Cout)[(size_t)row * N + col] = f2b(v);
        } else {
          // row = b*2048 + s ; store Vt[(b*N + col)*2048 + s]
          int bb = row >> 11, s = row & 2047;
          ((u16*)Cout)[((size_t)bb * N + col) * 2048 + s] = f2b(v);
        }
      }
}

// ---------------- causal GQA flash attention ----------------
// grid: (S/64, B*NH), block 256 (4 waves); wave w owns 16 q-rows.
// Q[4096][2048] bf16, K[4096][512] bf16, Vt[(b*512+kvh*128+d)][2048] bf16 -> AO[4096][2048] bf16
__global__ __launch_bounds__(256) void attn_fwd(const u16* __restrict__ Q, const u16* __restrict__ Kt,
                                                const u16* __restrict__ Vt, u16* __restrict__ AO) {
  const int l = threadIdx.x & 63, w = threadIdx.x >> 6;
  const int g = l >> 4, c = l & 15;
  const int bh = blockIdx.y;
  const int b = bh >> 4, h = bh & 15;
  const int kvh = h >> 2;
  const int q0 = blockIdx.x * 64 + w * 16;

  __shared__ u16 Plds[4][512];  // per-wave P tile [16 q][32 kv], chunk-swizzled
  u16* Pw = Plds[w];

  const float sm = 0.08838834764831845f * 1.4426950408889634f;  // 1/sqrt(128) * log2(e)

  bf16x8 qf[4];
  {
    const u16* qb = Q + ((size_t)(b * 2048 + q0 + c)) * 2048 + h * 128 + g * 8;
#pragma unroll
    for (int ks = 0; ks < 4; ++ks) qf[ks] = *(const bf16x8*)(qb + ks * 32);
  }

  f32x4 acc[8] = {};
  float mrow[4], lrow[4];
#pragma unroll
  for (int i = 0; i < 4; ++i) { mrow[i] = -1e30f; lrow[i] = 0.f; }

  const u16* Kb = Kt + (size_t)(b * 2048) * 512 + kvh * 128;
  const u16* Vb = Vt + (size_t)(b * 512 + kvh * 128) * 2048;

  for (int kv0 = 0; kv0 < q0 + 16; kv0 += 32) {
    f32x4 sacc[2] = {};
#pragma unroll
    for (int n = 0; n < 2; ++n) {
      const u16* kb = Kb + (size_t)(kv0 + n * 16 + c) * 512 + g * 8;
#pragma unroll
      for (int ks = 0; ks < 4; ++ks) {
        bf16x8 kf = *(const bf16x8*)(kb + ks * 32);
        sacc[n] = __builtin_amdgcn_mfma_f32_16x16x32_bf16(qf[ks], kf, sacc[n], 0, 0, 0);
      }
    }
    if (kv0 + 31 > q0) {  // diagonal tile: causal mask
#pragma unroll
      for (int n = 0; n < 2; ++n)
#pragma unroll
        for (int i = 0; i < 4; ++i) {
          int qrow = q0 + g * 4 + i;
          int kvcol = kv0 + n * 16 + c;
          if (kvcol > qrow) sacc[n][i] = -1e30f;
        }
    }
    float p[2][4], rs[4];
#pragma unroll
    for (int i = 0; i < 4; ++i) {
      float v = fmaxf(sacc[0][i], sacc[1][i]);
      v = fmaxf(v, __shfl_xor(v, 1));
      v = fmaxf(v, __shfl_xor(v, 2));
      v = fmaxf(v, __shfl_xor(v, 4));
      v = fmaxf(v, __shfl_xor(v, 8));
      float mn = fmaxf(mrow[i], v);
      rs[i] = exp2f((mrow[i] - mn) * sm);
      mrow[i] = mn;
    }
#pragma unroll
    for (int i = 0; i < 4; ++i) {
      p[0][i] = exp2f((sacc[0][i] - mrow[i]) * sm);
      p[1][i] = exp2f((sacc[1][i] - mrow[i]) * sm);
      float s = p[0][i] + p[1][i];
      s += __shfl_xor(s, 1);
      s += __shfl_xor(s, 2);
      s += __shfl_xor(s, 4);
      s += __shfl_xor(s, 8);
      lrow[i] = lrow[i] * rs[i] + s;
    }
#pragma unroll
    for (int f = 0; f < 8; ++f)
#pragma unroll
      for (int i = 0; i < 4; ++i) acc[f][i] *= rs[i];

    // P (rows g*4+i, col n*16+c) -> LDS with 16B-chunk swizzle, then read back as MFMA A-frag
#pragma unroll
    for (int n = 0; n < 2; ++n)
#pragma unroll
      for (int i = 0; i < 4; ++i) {
        int row = g * 4 + i, col = n * 16 + c;
        Pw[row * 32 + (((col >> 3) ^ ((row >> 1) & 3)) << 3) + (col & 7)] = f2b(p[n][i]);
      }
    asm volatile("s_waitcnt lgkmcnt(0)" ::: "memory");
    bf16x8 pa = *(const bf16x8*)(Pw + c * 32 + ((g ^ ((c >> 1) & 3)) << 3));
#pragma unroll
    for (int f = 0; f < 8; ++f) {
      const u16* vb = Vb + (size_t)(f * 16 + c) * 2048 + kv0 + g * 8;
      bf16x8 vf = *(const bf16x8*)vb;
      acc[f] = __builtin_amdgcn_mfma_f32_16x16x32_bf16(pa, vf, acc[f], 0, 0, 0);
    }
  }

#pragma unroll
  for (int i = 0; i < 4; ++i) {
    float inv = 1.0f / lrow[i];
    int qrow = q0 + g * 4 + i;
    u16* ob = AO + (size_t)(b * 2048 + qrow) * 2048 + h * 128 + c;
#pragma unroll
    for (int f = 0; f < 8; ++f) ob[(size_t)f * 16] = f2b(acc[f][i] * inv);
  }
}

// ---------------- host ----------------
extern "C" void kernel_launch(void* const* d_in, const int* in_sizes, int n_in,
                              void* d_out, int out_size, void* d_ws, size_t ws_size,
                              hipStream_t stream) {
  const float* X = (const float*)d_in[0];
  const float* Wq = (const float*)d_in[1];
  const float* Wk = (const float*)d_in[2];
  const float* Wv = (const float*)d_in[3];
  const float* Wo = (const float*)d_in[4];

  // workspace layout (u16 elements)
  u16* ws = (u16*)d_ws;
  const size_t nX = 8388608;   // 2*2048*2048
  const size_t nWq = 4194304;  // 2048*2048
  const size_t nWk = 1048576;  // 512*2048
  u16* Xb = ws;
  u16* Wqb = Xb + nX;
  u16* Wkb = Wqb + nWq;
  u16* Wvb = Wkb + nWk;
  u16* Wob = Wvb + nWk;
  u16* Qb = Wob + nWq;
  u16* Kb = Qb + nX;       // 4096*512
  u16* Vtb = Kb + 2097152; // 4096*512 transposed
  u16* AOb = Vtb + 2097152;
  if (ws_size < (size_t)(39845888) * 2) return;  // ~76 MB needed

  // fp32 -> bf16
  cvt_bf16<<<8192, 256, 0, stream>>>(X, Xb, (int)nX);
  cvt_bf16<<<4096, 256, 0, stream>>>(Wq, Wqb, (int)nWq);
  cvt_bf16<<<1024, 256, 0, stream>>>(Wk, Wkb, (int)nWk);
  cvt_bf16<<<1024, 256, 0, stream>>>(Wv, Wvb, (int)nWk);
  cvt_bf16<<<4096, 256, 0, stream>>>(Wo, Wob, (int)nWq);

  // projections
  gemm_bt<0><<<dim3(16, 32), 256, 0, stream>>>(Xb, Wqb, Qb, 4096, 2048, 2048);
  gemm_bt<0><<<dim3(4, 32), 256, 0, stream>>>(Xb, Wkb, Kb, 4096, 512, 2048);
  gemm_bt<1><<<dim3(4, 32), 256, 0, stream>>>(Xb, Wvb, Vtb, 4096, 512, 2048);

  // attention
  attn_fwd<<<dim3(32, 32), 256, 0, stream>>>(Qb, Kb, Vtb, AOb);

  // output projection -> fp32 d_out
  gemm_bt<2><<<dim3(16, 32), 256, 0, stream>>>(AOb, Wob, d_out, 4096, 2048, 2048);
}

// Round 2
// 457.697 us; speedup vs baseline: 1.7775x; 1.7775x over previous
//
#include <hip/hip_runtime.h>

typedef unsigned short u16;
typedef unsigned int u32;
typedef __attribute__((ext_vector_type(4))) float f32x4;
typedef __attribute__((ext_vector_type(8))) short bf16x8;

// Problem sizes (fixed): B=2, S=2048, D=2048, NH=16, NKV=4, HD=128

__device__ __forceinline__ u16 f2b(float f) {
  u32 u = __builtin_bit_cast(u32, f);
  u = (u + 0x7fffu + ((u >> 16) & 1u)) >> 16;  // RNE
  return (u16)u;
}

__device__ __forceinline__ void gload_lds16(const void* g, void* l) {
  __builtin_amdgcn_global_load_lds((const __attribute__((address_space(1))) u32*)g,
                                   (__attribute__((address_space(3))) u32*)l, 16, 0, 0);
}

// ---------------- fp32 -> bf16 conversion ----------------
__global__ void cvt_bf16(const float* __restrict__ src, u16* __restrict__ dst, int n) {
  int stride = gridDim.x * blockDim.x * 4;
  for (int idx = (blockIdx.x * blockDim.x + threadIdx.x) * 4; idx < n; idx += stride) {
    float4 v = *(const float4*)(src + idx);
    ushort4 o;
    o.x = f2b(v.x); o.y = f2b(v.y); o.z = f2b(v.z); o.w = f2b(v.w);
    *(ushort4*)(dst + idx) = o;
  }
}

// ---------------- GEMM: C[M,N] = A[M,K] * B[N,K]^T ----------------
template<int OUT_MODE>
__global__ __launch_bounds__(256) void gemm_bt(const u16* __restrict__ A, const u16* __restrict__ B,
                                               void* __restrict__ Cout, int M, int N, int Kd) {
  __shared__ u16 sA[128 * 32];
  __shared__ u16 sB[128 * 32];
  const int tid = threadIdx.x;
  const int l = tid & 63, w = tid >> 6;
  const int wr = w >> 1, wc = w & 1;
  const int g = l >> 4, c = l & 15;
  const int tm = blockIdx.y * 128, tn = blockIdx.x * 128;

  f32x4 acc[4][4] = {};

  const int r0 = tid >> 2, cc = (tid & 3) << 3;

  for (int k0 = 0; k0 < Kd; k0 += 32) {
    __syncthreads();
    {
      const u16* srcA0 = A + (size_t)(tm + r0) * Kd + k0 + cc;
      const u16* srcB0 = B + (size_t)(tn + r0) * Kd + k0 + cc;
      gload_lds16(srcA0, (char*)sA + w * 1024);
      gload_lds16(srcB0, (char*)sB + w * 1024);
      gload_lds16(srcA0 + (size_t)64 * Kd, (char*)sA + 4096 + w * 1024);
      gload_lds16(srcB0 + (size_t)64 * Kd, (char*)sB + 4096 + w * 1024);
    }
    __syncthreads();

    bf16x8 af[4], bfr[4];
#pragma unroll
    for (int m = 0; m < 4; ++m)
      af[m] = *(const bf16x8*)(sA + (wr * 64 + m * 16 + c) * 32 + g * 8);
#pragma unroll
    for (int n = 0; n < 4; ++n)
      bfr[n] = *(const bf16x8*)(sB + (wc * 64 + n * 16 + c) * 32 + g * 8);
#pragma unroll
    for (int m = 0; m < 4; ++m)
#pragma unroll
      for (int n = 0; n < 4; ++n)
        acc[m][n] = __builtin_amdgcn_mfma_f32_16x16x32_bf16(af[m], bfr[n], acc[m][n], 0, 0, 0);
  }

#pragma unroll
  for (int m = 0; m < 4; ++m)
#pragma unroll
    for (int n = 0; n < 4; ++n)
#pragma unroll
      for (int i = 0; i < 4; ++i) {
        int row = tm + wr * 64 + m * 16 + g * 4 + i;
        int col = tn + wc * 64 + n * 16 + c;
        float v = acc[m][n][i];
        if constexpr (OUT_MODE == 2) {
          ((float*)Cout)[(size_t)row * N + col] = v;
        } else if constexpr (OUT_MODE == 0) {
          ((u16*)Cout)[(size_t)row * N + col] = f2b(v);
        } else {
          int bb = row >> 11, s = row & 2047;
          ((u16*)Cout)[((size_t)bb * N + col) * 2048 + s] = f2b(v);
        }
      }
}

// ---------------- causal GQA flash attention (swapped-QK^T, lane-local softmax) ----------------
// grid: (16, B*NH), block 256 (4 waves). Block x handles q-tiles {x, 31-x} (causal balance).
// Wave w owns 16 q-rows of each tile. Per lane: q = q0 + (lane&15); m,l are scalars.
// Q[4096][2048], K[4096][512], Vt[(b*512+kvh*128+d)][2048] bf16 -> AO[4096][2048] bf16
__global__ __launch_bounds__(256) void attn_fwd(const u16* __restrict__ Q, const u16* __restrict__ Kt,
                                                const u16* __restrict__ Vt, u16* __restrict__ AO) {
  const int l = threadIdx.x & 63, w = threadIdx.x >> 6;
  const int g = l >> 4, c = l & 15;
  const int bh = blockIdx.y;
  const int b = bh >> 4, h = bh & 15;
  const int kvh = h >> 2;

  const float sm = 0.08838834764831845f * 1.4426950408889634f;  // 1/sqrt(128) * log2(e)

  const u16* Kb = Kt + (size_t)(b * 2048) * 512 + kvh * 128;
  const u16* Vb = Vt + (size_t)(b * 512 + kvh * 128) * 2048;

  // bpermute source lanes (byte-address semantics handled by __shfl)
  const int src0 = (g & 1) * 32 + c;   // lane holding quad 2g
  const int src1 = src0 + 16;          // lane holding quad 2g+1
  const int n_sel = g >> 1;

  for (int half = 0; half < 2; ++half) {
    const int tile = half ? (31 - blockIdx.x) : blockIdx.x;
    const int q0 = tile * 64 + w * 16;

    // Q fragment (B-operand: row=c=q, col=g*8+j, k-chunks ks*32)
    bf16x8 qf[4];
    {
      const u16* qb = Q + ((size_t)(b * 2048 + q0 + c)) * 2048 + h * 128 + g * 8;
#pragma unroll
      for (int ks = 0; ks < 4; ++ks) qf[ks] = *(const bf16x8*)(qb + ks * 32);
    }

    f32x4 acc[8] = {};
    float mrow = -1e30f, lrow = 0.f;

    for (int kv0 = 0; kv0 < q0 + 16; kv0 += 32) {
      // K fragments (A-operand: row=c=kv, col=g*8+j)
      bf16x8 kf[2][4];
#pragma unroll
      for (int n = 0; n < 2; ++n) {
        const u16* kb = Kb + (size_t)(kv0 + n * 16 + c) * 512 + g * 8;
#pragma unroll
        for (int ks = 0; ks < 4; ++ks) kf[n][ks] = *(const bf16x8*)(kb + ks * 32);
      }
      // V fragments (B-operand: row=c=d within f*16, col=g*8+j over kv) — issue early
      bf16x8 vf[8];
#pragma unroll
      for (int f = 0; f < 8; ++f)
        vf[f] = *(const bf16x8*)(Vb + (size_t)(f * 16 + c) * 2048 + kv0 + g * 8);

      // S^T tile: sacc[n][i] = S[kv = kv0+n*16+g*4+i][q = q0+c]
      f32x4 sacc[2] = {};
#pragma unroll
      for (int n = 0; n < 2; ++n)
#pragma unroll
        for (int ks = 0; ks < 4; ++ks)
          sacc[n] = __builtin_amdgcn_mfma_f32_16x16x32_bf16(kf[n][ks], qf[ks], sacc[n], 0, 0, 0);

      if (kv0 + 31 > q0) {  // diagonal tiles: causal mask
        const int qq = q0 + c;
#pragma unroll
        for (int n = 0; n < 2; ++n)
#pragma unroll
          for (int i = 0; i < 4; ++i)
            if (kv0 + n * 16 + g * 4 + i > qq) sacc[n][i] = -1e30f;
      }

      // lane-local max over 8 values, then reduce across g (xor 16, 32)
      float mx = fmaxf(fmaxf(fmaxf(sacc[0][0], sacc[0][1]), fmaxf(sacc[0][2], sacc[0][3])),
                       fmaxf(fmaxf(sacc[1][0], sacc[1][1]), fmaxf(sacc[1][2], sacc[1][3])));
      mx = fmaxf(mx, __shfl_xor(mx, 16));
      mx = fmaxf(mx, __shfl_xor(mx, 32));
      float mnew = fmaxf(mrow, mx);
      float rs = exp2f((mrow - mnew) * sm);
      mrow = mnew;

      float p[2][4];
      float psum = 0.f;
#pragma unroll
      for (int n = 0; n < 2; ++n)
#pragma unroll
        for (int i = 0; i < 4; ++i) {
          p[n][i] = exp2f((sacc[n][i] - mrow) * sm);
          psum += p[n][i];
        }
      psum += __shfl_xor(psum, 16);
      psum += __shfl_xor(psum, 32);
      lrow = lrow * rs + psum;

      // rescale O accumulator: element (f,i) is q = g*4+i -> broadcast rs from lane c'=g*4+i
      float rsb[4];
#pragma unroll
      for (int i = 0; i < 4; ++i) rsb[i] = __shfl(rs, (g << 4) + (g << 2) + i);
#pragma unroll
      for (int f = 0; f < 8; ++f)
#pragma unroll
        for (int i = 0; i < 4; ++i) acc[f][i] *= rsb[i];

      // pack P to bf16 pairs: w[n][h] covers kv = kv0+n*16+g*4+{2h,2h+1}
      u32 wp[2][2];
#pragma unroll
      for (int n = 0; n < 2; ++n)
#pragma unroll
        for (int hh = 0; hh < 2; ++hh)
          wp[n][hh] = (u32)f2b(p[n][2 * hh]) | ((u32)f2b(p[n][2 * hh + 1]) << 16);

      // redistribute to PV A-fragment: lane needs kv = g*8..g*8+7 for q=c
      union { bf16x8 v; u32 u[4]; } pa;
      {
        int a00 = __shfl((int)wp[0][0], src0), a01 = __shfl((int)wp[0][1], src0);
        int a10 = __shfl((int)wp[1][0], src0), a11 = __shfl((int)wp[1][1], src0);
        int b00 = __shfl((int)wp[0][0], src1), b01 = __shfl((int)wp[0][1], src1);
        int b10 = __shfl((int)wp[1][0], src1), b11 = __shfl((int)wp[1][1], src1);
        pa.u[0] = (u32)(n_sel ? a10 : a00);
        pa.u[1] = (u32)(n_sel ? a11 : a01);
        pa.u[2] = (u32)(n_sel ? b10 : b00);
        pa.u[3] = (u32)(n_sel ? b11 : b01);
      }

      // PV: acc[f] = O[q=g*4+i][d=f*16+c]
#pragma unroll
      for (int f = 0; f < 8; ++f)
        acc[f] = __builtin_amdgcn_mfma_f32_16x16x32_bf16(pa.v, vf[f], acc[f], 0, 0, 0);
    }

    // epilogue: divide by l (broadcast per i) and store
    float inv = 1.0f / lrow;
    float invb[4];
#pragma unroll
    for (int i = 0; i < 4; ++i) invb[i] = __shfl(inv, (g << 4) + (g << 2) + i);
#pragma unroll
    for (int i = 0; i < 4; ++i) {
      int qrow = q0 + g * 4 + i;
      u16* ob = AO + (size_t)(b * 2048 + qrow) * 2048 + h * 128 + c;
#pragma unroll
      for (int f = 0; f < 8; ++f) ob[(size_t)f * 16] = f2b(acc[f][i] * invb[i]);
    }
  }
}

// ---------------- host ----------------
extern "C" void kernel_launch(void* const* d_in, const int* in_sizes, int n_in,
                              void* d_out, int out_size, void* d_ws, size_t ws_size,
                              hipStream_t stream) {
  const float* X = (const float*)d_in[0];
  const float* Wq = (const float*)d_in[1];
  const float* Wk = (const float*)d_in[2];
  const float* Wv = (const float*)d_in[3];
  const float* Wo = (const float*)d_in[4];

  u16* ws = (u16*)d_ws;
  const size_t nX = 8388608;   // 2*2048*2048
  const size_t nWq = 4194304;  // 2048*2048
  const size_t nWk = 1048576;  // 512*2048
  u16* Xb = ws;
  u16* Wqb = Xb + nX;
  u16* Wkb = Wqb + nWq;
  u16* Wvb = Wkb + nWk;
  u16* Wob = Wvb + nWk;
  u16* Qb = Wob + nWq;
  u16* Kb = Qb + nX;
  u16* Vtb = Kb + 2097152;
  u16* AOb = Vtb + 2097152;
  if (ws_size < (size_t)(39845888) * 2) return;

  cvt_bf16<<<8192, 256, 0, stream>>>(X, Xb, (int)nX);
  cvt_bf16<<<4096, 256, 0, stream>>>(Wq, Wqb, (int)nWq);
  cvt_bf16<<<1024, 256, 0, stream>>>(Wk, Wkb, (int)nWk);
  cvt_bf16<<<1024, 256, 0, stream>>>(Wv, Wvb, (int)nWk);
  cvt_bf16<<<4096, 256, 0, stream>>>(Wo, Wob, (int)nWq);

  gemm_bt<0><<<dim3(16, 32), 256, 0, stream>>>(Xb, Wqb, Qb, 4096, 2048, 2048);
  gemm_bt<0><<<dim3(4, 32), 256, 0, stream>>>(Xb, Wkb, Kb, 4096, 512, 2048);
  gemm_bt<1><<<dim3(4, 32), 256, 0, stream>>>(Xb, Wvb, Vtb, 4096, 512, 2048);

  attn_fwd<<<dim3(16, 32), 256, 0, stream>>>(Qb, Kb, Vtb, AOb);

  gemm_bt<2><<<dim3(16, 32), 256, 0, stream>>>(AOb, Wob, d_out, 4096, 2048, 2048);
}

// Round 3
// 456.173 us; speedup vs baseline: 1.7834x; 1.0033x over previous
//
#include <hip/hip_runtime.h>

typedef unsigned short u16;
typedef unsigned int u32;
typedef __attribute__((ext_vector_type(4))) float f32x4;
typedef __attribute__((ext_vector_type(8))) short bf16x8;

// Problem sizes (fixed): B=2, S=2048, D=2048, NH=16, NKV=4, HD=128

__device__ __forceinline__ u16 f2b(float f) {
  u32 u = __builtin_bit_cast(u32, f);
  u = (u + 0x7fffu + ((u >> 16) & 1u)) >> 16;  // RNE
  return (u16)u;
}

__device__ __forceinline__ void gload_lds16(const void* g, void* l) {
  __builtin_amdgcn_global_load_lds((const __attribute__((address_space(1))) u32*)g,
                                   (__attribute__((address_space(3))) u32*)l, 16, 0, 0);
}

// ---------------- fp32 -> bf16 conversion ----------------
__global__ void cvt_bf16(const float* __restrict__ src, u16* __restrict__ dst, int n) {
  int stride = gridDim.x * blockDim.x * 4;
  for (int idx = (blockIdx.x * blockDim.x + threadIdx.x) * 4; idx < n; idx += stride) {
    float4 v = *(const float4*)(src + idx);
    ushort4 o;
    o.x = f2b(v.x); o.y = f2b(v.y); o.z = f2b(v.z); o.w = f2b(v.w);
    *(ushort4*)(dst + idx) = o;
  }
}

// ---------------- GEMM: C[M,N] = A[M,K] * B[N,K]^T ----------------
template<int OUT_MODE>
__global__ __launch_bounds__(256) void gemm_bt(const u16* __restrict__ A, const u16* __restrict__ B,
                                               void* __restrict__ Cout, int M, int N, int Kd) {
  __shared__ u16 sA[128 * 32];
  __shared__ u16 sB[128 * 32];
  const int tid = threadIdx.x;
  const int l = tid & 63, w = tid >> 6;
  const int wr = w >> 1, wc = w & 1;
  const int g = l >> 4, c = l & 15;
  const int tm = blockIdx.y * 128, tn = blockIdx.x * 128;

  f32x4 acc[4][4] = {};

  const int r0 = tid >> 2, cc = (tid & 3) << 3;

  for (int k0 = 0; k0 < Kd; k0 += 32) {
    __syncthreads();
    {
      const u16* srcA0 = A + (size_t)(tm + r0) * Kd + k0 + cc;
      const u16* srcB0 = B + (size_t)(tn + r0) * Kd + k0 + cc;
      gload_lds16(srcA0, (char*)sA + w * 1024);
      gload_lds16(srcB0, (char*)sB + w * 1024);
      gload_lds16(srcA0 + (size_t)64 * Kd, (char*)sA + 4096 + w * 1024);
      gload_lds16(srcB0 + (size_t)64 * Kd, (char*)sB + 4096 + w * 1024);
    }
    __syncthreads();

    bf16x8 af[4], bfr[4];
#pragma unroll
    for (int m = 0; m < 4; ++m)
      af[m] = *(const bf16x8*)(sA + (wr * 64 + m * 16 + c) * 32 + g * 8);
#pragma unroll
    for (int n = 0; n < 4; ++n)
      bfr[n] = *(const bf16x8*)(sB + (wc * 64 + n * 16 + c) * 32 + g * 8);
#pragma unroll
    for (int m = 0; m < 4; ++m)
#pragma unroll
      for (int n = 0; n < 4; ++n)
        acc[m][n] = __builtin_amdgcn_mfma_f32_16x16x32_bf16(af[m], bfr[n], acc[m][n], 0, 0, 0);
  }

#pragma unroll
  for (int m = 0; m < 4; ++m)
#pragma unroll
    for (int n = 0; n < 4; ++n)
#pragma unroll
      for (int i = 0; i < 4; ++i) {
        int row = tm + wr * 64 + m * 16 + g * 4 + i;
        int col = tn + wc * 64 + n * 16 + c;
        float v = acc[m][n][i];
        if constexpr (OUT_MODE == 2) {
          ((float*)Cout)[(size_t)row * N + col] = v;
        } else if constexpr (OUT_MODE == 0) {
          ((u16*)Cout)[(size_t)row * N + col] = f2b(v);
        } else {
          int bb = row >> 11, s = row & 2047;
          ((u16*)Cout)[((size_t)bb * N + col) * 2048 + s] = f2b(v);
        }
      }
}

// ---------------- causal GQA flash attention (swapped-QK^T, lane-local softmax) ----------------
// grid: (16, B*NH), block 512 (8 waves). Waves 0-3 handle q-tile x, waves 4-7 tile 31-x
// (causal balance; each SIMD hosts one short + one long wave). Wave owns 16 q-rows.
// Per lane: q = q0 + (lane&15); m,l are lane-local scalars.
// Q[4096][2048], K[4096][512], Vt[(b*512+kvh*128+d)][2048] bf16 -> AO[4096][2048] bf16
__global__ __launch_bounds__(512) void attn_fwd(const u16* __restrict__ Q, const u16* __restrict__ Kt,
                                                const u16* __restrict__ Vt, u16* __restrict__ AO) {
  const int l = threadIdx.x & 63, w = threadIdx.x >> 6;
  const int g = l >> 4, c = l & 15;
  const int bh = blockIdx.y;
  const int b = bh >> 4, h = bh & 15;
  const int kvh = h >> 2;

  const float sm = 0.08838834764831845f * 1.4426950408889634f;  // 1/sqrt(128) * log2(e)

  const u16* Kb = Kt + (size_t)(b * 2048) * 512 + kvh * 128;
  const u16* Vb = Vt + (size_t)(b * 512 + kvh * 128) * 2048;

  const int src0 = (g & 1) * 32 + c;   // lane holding quad 2g
  const int src1 = src0 + 16;          // lane holding quad 2g+1
  const int n_sel = g >> 1;

  const int tile = (w >> 2) ? (31 - blockIdx.x) : blockIdx.x;
  const int q0 = tile * 64 + (w & 3) * 16;

  // Q fragment (B-operand: row=c=q, col=g*8+j, k-chunks ks*32)
  bf16x8 qf[4];
  {
    const u16* qb = Q + ((size_t)(b * 2048 + q0 + c)) * 2048 + h * 128 + g * 8;
#pragma unroll
    for (int ks = 0; ks < 4; ++ks) qf[ks] = *(const bf16x8*)(qb + ks * 32);
  }

  f32x4 acc[8] = {};
  float mrow = -1e30f, lrow = 0.f;

  for (int kv0 = 0; kv0 < q0 + 16; kv0 += 32) {
    // K fragments (A-operand: row=c=kv, col=g*8+j)
    bf16x8 kf[2][4];
#pragma unroll
    for (int n = 0; n < 2; ++n) {
      const u16* kb = Kb + (size_t)(kv0 + n * 16 + c) * 512 + g * 8;
#pragma unroll
      for (int ks = 0; ks < 4; ++ks) kf[n][ks] = *(const bf16x8*)(kb + ks * 32);
    }
    // V fragments (B-operand: row=c=d within f*16, col=g*8+j over kv) — issue early
    bf16x8 vf[8];
#pragma unroll
    for (int f = 0; f < 8; ++f)
      vf[f] = *(const bf16x8*)(Vb + (size_t)(f * 16 + c) * 2048 + kv0 + g * 8);

    // S^T tile: sacc[n][i] = S[kv = kv0+n*16+g*4+i][q = q0+c]
    f32x4 sacc[2] = {};
    __builtin_amdgcn_s_setprio(1);
#pragma unroll
    for (int n = 0; n < 2; ++n)
#pragma unroll
      for (int ks = 0; ks < 4; ++ks)
        sacc[n] = __builtin_amdgcn_mfma_f32_16x16x32_bf16(kf[n][ks], qf[ks], sacc[n], 0, 0, 0);
    __builtin_amdgcn_s_setprio(0);

    if (kv0 + 31 > q0) {  // diagonal tiles: causal mask
      const int qq = q0 + c;
#pragma unroll
      for (int n = 0; n < 2; ++n)
#pragma unroll
        for (int i = 0; i < 4; ++i)
          if (kv0 + n * 16 + g * 4 + i > qq) sacc[n][i] = -1e30f;
    }

    // lane-local max over 8 values, then reduce across g (xor 16, 32)
    float mx = fmaxf(fmaxf(fmaxf(sacc[0][0], sacc[0][1]), fmaxf(sacc[0][2], sacc[0][3])),
                     fmaxf(fmaxf(sacc[1][0], sacc[1][1]), fmaxf(sacc[1][2], sacc[1][3])));
    mx = fmaxf(mx, __shfl_xor(mx, 16));
    mx = fmaxf(mx, __shfl_xor(mx, 32));

    // T13 defer-max: skip O-rescale while (mx - m)*sm <= 8 (P bounded by 2^8; fp32 accum fine)
    if (!__all((mx - mrow) * sm <= 8.0f)) {
      float mnew = fmaxf(mrow, mx);
      float rs = exp2f((mrow - mnew) * sm);
      mrow = mnew;
      lrow *= rs;
      float rsb[4];
#pragma unroll
      for (int i = 0; i < 4; ++i) rsb[i] = __shfl(rs, (g << 4) + (g << 2) + i);
#pragma unroll
      for (int f = 0; f < 8; ++f)
#pragma unroll
        for (int i = 0; i < 4; ++i) acc[f][i] *= rsb[i];
    }

    float p[2][4];
    float psum = 0.f;
#pragma unroll
    for (int n = 0; n < 2; ++n)
#pragma unroll
      for (int i = 0; i < 4; ++i) {
        p[n][i] = exp2f((sacc[n][i] - mrow) * sm);
        psum += p[n][i];
      }
    psum += __shfl_xor(psum, 16);
    psum += __shfl_xor(psum, 32);
    lrow += psum;

    // pack P to bf16 pairs: wp[n][h] covers kv = kv0+n*16+g*4+{2h,2h+1}
    u32 wp[2][2];
#pragma unroll
    for (int n = 0; n < 2; ++n)
#pragma unroll
      for (int hh = 0; hh < 2; ++hh)
        wp[n][hh] = (u32)f2b(p[n][2 * hh]) | ((u32)f2b(p[n][2 * hh + 1]) << 16);

    // redistribute to PV A-fragment: lane needs kv = g*8..g*8+7 for q=c
    union { bf16x8 v; u32 u[4]; } pa;
    {
      int a00 = __shfl((int)wp[0][0], src0), a01 = __shfl((int)wp[0][1], src0);
      int a10 = __shfl((int)wp[1][0], src0), a11 = __shfl((int)wp[1][1], src0);
      int b00 = __shfl((int)wp[0][0], src1), b01 = __shfl((int)wp[0][1], src1);
      int b10 = __shfl((int)wp[1][0], src1), b11 = __shfl((int)wp[1][1], src1);
      pa.u[0] = (u32)(n_sel ? a10 : a00);
      pa.u[1] = (u32)(n_sel ? a11 : a01);
      pa.u[2] = (u32)(n_sel ? b10 : b00);
      pa.u[3] = (u32)(n_sel ? b11 : b01);
    }

    // PV: acc[f] = O[q=g*4+i][d=f*16+c]
    __builtin_amdgcn_s_setprio(1);
#pragma unroll
    for (int f = 0; f < 8; ++f)
      acc[f] = __builtin_amdgcn_mfma_f32_16x16x32_bf16(pa.v, vf[f], acc[f], 0, 0, 0);
    __builtin_amdgcn_s_setprio(0);
  }

  // epilogue: divide by l (broadcast per i) and store
  float inv = 1.0f / lrow;
  float invb[4];
#pragma unroll
  for (int i = 0; i < 4; ++i) invb[i] = __shfl(inv, (g << 4) + (g << 2) + i);
#pragma unroll
  for (int i = 0; i < 4; ++i) {
    int qrow = q0 + g * 4 + i;
    u16* ob = AO + (size_t)(b * 2048 + qrow) * 2048 + h * 128 + c;
#pragma unroll
    for (int f = 0; f < 8; ++f) ob[(size_t)f * 16] = f2b(acc[f][i] * invb[i]);
  }
}

// ---------------- host ----------------
extern "C" void kernel_launch(void* const* d_in, const int* in_sizes, int n_in,
                              void* d_out, int out_size, void* d_ws, size_t ws_size,
                              hipStream_t stream) {
  const float* X = (const float*)d_in[0];
  const float* Wq = (const float*)d_in[1];
  const float* Wk = (const float*)d_in[2];
  const float* Wv = (const float*)d_in[3];
  const float* Wo = (const float*)d_in[4];

  u16* ws = (u16*)d_ws;
  const size_t nX = 8388608;   // 2*2048*2048
  const size_t nWq = 4194304;  // 2048*2048
  const size_t nWk = 1048576;  // 512*2048
  u16* Xb = ws;
  u16* Wqb = Xb + nX;
  u16* Wkb = Wqb + nWq;
  u16* Wvb = Wkb + nWk;
  u16* Wob = Wvb + nWk;
  u16* Qb = Wob + nWq;
  u16* Kb = Qb + nX;
  u16* Vtb = Kb + 2097152;
  u16* AOb = Vtb + 2097152;
  if (ws_size < (size_t)(39845888) * 2) return;

  cvt_bf16<<<8192, 256, 0, stream>>>(X, Xb, (int)nX);
  cvt_bf16<<<4096, 256, 0, stream>>>(Wq, Wqb, (int)nWq);
  cvt_bf16<<<1024, 256, 0, stream>>>(Wk, Wkb, (int)nWk);
  cvt_bf16<<<1024, 256, 0, stream>>>(Wv, Wvb, (int)nWk);
  cvt_bf16<<<4096, 256, 0, stream>>>(Wo, Wob, (int)nWq);

  gemm_bt<0><<<dim3(16, 32), 256, 0, stream>>>(Xb, Wqb, Qb, 4096, 2048, 2048);
  gemm_bt<0><<<dim3(4, 32), 256, 0, stream>>>(Xb, Wkb, Kb, 4096, 512, 2048);
  gemm_bt<1><<<dim3(4, 32), 256, 0, stream>>>(Xb, Wvb, Vtb, 4096, 512, 2048);

  attn_fwd<<<dim3(16, 32), 512, 0, stream>>>(Qb, Kb, Vtb, AOb);

  gemm_bt<2><<<dim3(16, 32), 256, 0, stream>>>(AOb, Wob, d_out, 4096, 2048, 2048);
}

// Round 5
// 352.081 us; speedup vs baseline: 2.3107x; 1.2956x over previous
//
#include <hip/hip_runtime.h>

typedef unsigned short u16;
typedef unsigned int u32;
typedef __attribute__((ext_vector_type(4))) float f32x4;
typedef __attribute__((ext_vector_type(16))) float f32x16;
typedef __attribute__((ext_vector_type(8))) short bf16x8;

// Problem sizes (fixed): B=2, S=2048, D=2048, NH=16, NKV=4, HD=128

__device__ __forceinline__ u16 f2b(float f) {
  u32 u = __builtin_bit_cast(u32, f);
  u = (u + 0x7fffu + ((u >> 16) & 1u)) >> 16;  // RNE
  return (u16)u;
}

__device__ __forceinline__ void gload_lds16(const void* g, void* l) {
  __builtin_amdgcn_global_load_lds((const __attribute__((address_space(1))) u32*)g,
                                   (__attribute__((address_space(3))) u32*)l, 16, 0, 0);
}

// ---------------- fp32 -> bf16 conversion ----------------
__global__ void cvt_bf16(const float* __restrict__ src, u16* __restrict__ dst, int n) {
  int stride = gridDim.x * blockDim.x * 4;
  for (int idx = (blockIdx.x * blockDim.x + threadIdx.x) * 4; idx < n; idx += stride) {
    float4 v = *(const float4*)(src + idx);
    ushort4 o;
    o.x = f2b(v.x); o.y = f2b(v.y); o.z = f2b(v.z); o.w = f2b(v.w);
    *(ushort4*)(dst + idx) = o;
  }
}

// ---------------- GEMM: C[M,N] = A[M,K] * B[N,K]^T ----------------
template<int OUT_MODE>
__global__ __launch_bounds__(256) void gemm_bt(const u16* __restrict__ A, const u16* __restrict__ B,
                                               void* __restrict__ Cout, int M, int N, int Kd) {
  __shared__ u16 sA[128 * 32];
  __shared__ u16 sB[128 * 32];
  const int tid = threadIdx.x;
  const int l = tid & 63, w = tid >> 6;
  const int wr = w >> 1, wc = w & 1;
  const int g = l >> 4, c = l & 15;
  const int tm = blockIdx.y * 128, tn = blockIdx.x * 128;

  f32x4 acc[4][4] = {};

  const int r0 = tid >> 2, cc = (tid & 3) << 3;

  for (int k0 = 0; k0 < Kd; k0 += 32) {
    __syncthreads();
    {
      const u16* srcA0 = A + (size_t)(tm + r0) * Kd + k0 + cc;
      const u16* srcB0 = B + (size_t)(tn + r0) * Kd + k0 + cc;
      gload_lds16(srcA0, (char*)sA + w * 1024);
      gload_lds16(srcB0, (char*)sB + w * 1024);
      gload_lds16(srcA0 + (size_t)64 * Kd, (char*)sA + 4096 + w * 1024);
      gload_lds16(srcB0 + (size_t)64 * Kd, (char*)sB + 4096 + w * 1024);
    }
    __syncthreads();

    bf16x8 af[4], bfr[4];
#pragma unroll
    for (int m = 0; m < 4; ++m)
      af[m] = *(const bf16x8*)(sA + (wr * 64 + m * 16 + c) * 32 + g * 8);
#pragma unroll
    for (int n = 0; n < 4; ++n)
      bfr[n] = *(const bf16x8*)(sB + (wc * 64 + n * 16 + c) * 32 + g * 8);
#pragma unroll
    for (int m = 0; m < 4; ++m)
#pragma unroll
      for (int n = 0; n < 4; ++n)
        acc[m][n] = __builtin_amdgcn_mfma_f32_16x16x32_bf16(af[m], bfr[n], acc[m][n], 0, 0, 0);
  }

#pragma unroll
  for (int m = 0; m < 4; ++m)
#pragma unroll
    for (int n = 0; n < 4; ++n)
#pragma unroll
      for (int i = 0; i < 4; ++i) {
        int row = tm + wr * 64 + m * 16 + g * 4 + i;
        int col = tn + wc * 64 + n * 16 + c;
        float v = acc[m][n][i];
        if constexpr (OUT_MODE == 2) {
          ((float*)Cout)[(size_t)row * N + col] = v;
        } else if constexpr (OUT_MODE == 0) {
          ((u16*)Cout)[(size_t)row * N + col] = f2b(v);
        } else {
          int bb = row >> 11, s = row & 2047;
          ((u16*)Cout)[((size_t)bb * N + col) * 2048 + s] = f2b(v);
        }
      }
}

// ---------------- causal GQA flash attention: 32x32 swapped-operand, register-resident -------
// grid (16, B*NH), block 256 (4 waves). Waves 0,1 -> 64-row tile x; waves 2,3 -> tile 31-x.
// Lane owns q = q0 + (lane&31) throughout (S^T and O^T both have col = lane&31), so softmax
// state m,l and all rescales are lane-local. Cross-lane traffic per 32q x 32kv tile:
// 2 shfl_xor(32) reductions + 8 shfl_xor(32) for the P-fragment redistribution.
// QK^T: S^T = mfma32x32x16(K_frag, Q_frag) over 8 k-chunks.
// PV:  O^T = mfma32x32x16(Vt_frag, P_frag) — P words feed the B-operand directly.
__global__ __launch_bounds__(256, 2) void attn_fwd(const u16* __restrict__ Q, const u16* __restrict__ Kt,
                                                   const u16* __restrict__ Vt, u16* __restrict__ AO) {
  const int l = threadIdx.x & 63, w = threadIdx.x >> 6;
  const int ql = l & 31, hi = l >> 5;
  const int bh = blockIdx.y;
  const int b = bh >> 4, h = bh & 15;
  const int kvh = h >> 2;

  const float sm = 0.08838834764831845f * 1.4426950408889634f;  // 1/sqrt(128) * log2(e)

  const u16* Kb = Kt + (size_t)(b * 2048) * 512 + kvh * 128;
  const u16* Vb = Vt + (size_t)(b * 512 + kvh * 128) * 2048;

  const int tile = (w < 2) ? blockIdx.x : (31 - blockIdx.x);
  const int q0 = tile * 64 + (w & 1) * 32;

  // Q fragments (B-operand of QK: col=q=lane&31, k = ck*16 + hi*8 + j)
  bf16x8 qf[8];
  {
    const u16* qb = Q + ((size_t)(b * 2048 + q0 + ql)) * 2048 + h * 128 + hi * 8;
#pragma unroll
    for (int ck = 0; ck < 8; ++ck) qf[ck] = *(const bf16x8*)(qb + ck * 16);
  }

  f32x16 acc[4] = {};  // O^T[d = db*32 + crow(r)][q = q0 + (lane&31)]
  float mrow = -1e30f, lrow = 0.f;

  for (int kv0 = 0; kv0 <= q0; kv0 += 32) {
    // K fragments (A-operand: row=kv=lane&31, k = ck*16 + hi*8 + j)
    bf16x8 kf[8];
    {
      const u16* kb = Kb + (size_t)(kv0 + ql) * 512 + hi * 8;
#pragma unroll
      for (int ck = 0; ck < 8; ++ck) kf[ck] = *(const bf16x8*)(kb + ck * 16);
    }
    // V^T fragments (A-operand of PV: row=d=db*32+(lane&31), k=kv=ks*16+hi*8+j)
    bf16x8 vtf[2][4];
    {
      const u16* vb = Vb + (size_t)ql * 2048 + kv0 + hi * 8;
#pragma unroll
      for (int ks = 0; ks < 2; ++ks)
#pragma unroll
        for (int db = 0; db < 4; ++db)
          vtf[ks][db] = *(const bf16x8*)(vb + (size_t)(db * 32) * 2048 + ks * 16);
    }

    // S^T: lane holds S[kv0 + crow(r)][q0 + lane&31], crow(r) = (r&3)+8*(r>>2)+4*hi
    f32x16 sacc = {};
    __builtin_amdgcn_s_setprio(1);
#pragma unroll
    for (int ck = 0; ck < 8; ++ck)
      sacc = __builtin_amdgcn_mfma_f32_32x32x16_bf16(kf[ck], qf[ck], sacc, 0, 0, 0);
    __builtin_amdgcn_s_setprio(0);

    if (kv0 == q0) {  // diagonal tile: mask kv > q
#pragma unroll
      for (int r = 0; r < 16; ++r) {
        int crow = (r & 3) + 8 * (r >> 2) + 4 * hi;
        if (crow > ql) sacc[r] = -1e30f;
      }
    }

    // max over kv: 15 local fmax + 1 cross-half exchange (same q in lane and lane^32)
    float mx = sacc[0];
#pragma unroll
    for (int r = 1; r < 16; ++r) mx = fmaxf(mx, sacc[r]);
    mx = fmaxf(mx, __shfl_xor(mx, 32));

    // T13 defer-max: rescale only when needed (P bounded by 2^8)
    if (!__all((mx - mrow) * sm <= 8.0f)) {
      float mnew = fmaxf(mrow, mx);
      float rs = exp2f((mrow - mnew) * sm);  // lane-local (per-q)
      mrow = mnew;
      lrow *= rs;
#pragma unroll
      for (int db = 0; db < 4; ++db)
#pragma unroll
        for (int r = 0; r < 16; ++r) acc[db][r] *= rs;
    }

    // P = exp2((S - m)*sm); lane-local sum + cross-half
    float p[16];
    float psum = 0.f;
#pragma unroll
    for (int r = 0; r < 16; ++r) {
      p[r] = exp2f((sacc[r] - mrow) * sm);
      psum += p[r];
    }
    psum += __shfl_xor(psum, 32);
    lrow += psum;

    // pack P pairs (consecutive kv within this lane's crow set):
    // hi=0 lane: a0..a3 = kv{0,1},{2,3},{8,9},{10,11}; b0..b3 = kv{16,17},{18,19},{24,25},{26,27}
    // hi=1 lane: a0..a3 = kv{4,5},{6,7},{12,13},{14,15}; b0..b3 = kv{20..23},{28..31}
    u32 a0 = (u32)f2b(p[0]) | ((u32)f2b(p[1]) << 16);
    u32 a1 = (u32)f2b(p[2]) | ((u32)f2b(p[3]) << 16);
    u32 a2 = (u32)f2b(p[4]) | ((u32)f2b(p[5]) << 16);
    u32 a3 = (u32)f2b(p[6]) | ((u32)f2b(p[7]) << 16);
    u32 b0 = (u32)f2b(p[8]) | ((u32)f2b(p[9]) << 16);
    u32 b1 = (u32)f2b(p[10]) | ((u32)f2b(p[11]) << 16);
    u32 b2 = (u32)f2b(p[12]) | ((u32)f2b(p[13]) << 16);
    u32 b3 = (u32)f2b(p[14]) | ((u32)f2b(p[15]) << 16);

    // cross-half exchange: partner lane (same q, other hi) holds the other 16 kv
    u32 xa0 = (u32)__shfl_xor((int)a0, 32), xa1 = (u32)__shfl_xor((int)a1, 32);
    u32 xa2 = (u32)__shfl_xor((int)a2, 32), xa3 = (u32)__shfl_xor((int)a3, 32);
    u32 xb0 = (u32)__shfl_xor((int)b0, 32), xb1 = (u32)__shfl_xor((int)b1, 32);
    u32 xb2 = (u32)__shfl_xor((int)b2, 32), xb3 = (u32)__shfl_xor((int)b3, 32);

    // B-operand fragment: lane (q,hi) supplies k = hi*8 + j
    // pa0 (ks=0, kv 0..15): hi=0 -> kv{0..7} = [a0,a1,xa0,xa1]; hi=1 -> kv{8..15} = [xa2,xa3,a2,a3]
    // pa1 (ks=1, kv 16..31): hi=0 -> [b0,b1,xb0,xb1]; hi=1 -> [xb2,xb3,b2,b3]
    union { bf16x8 v; u32 u[4]; } pa0, pa1;
    pa0.u[0] = hi ? xa2 : a0;
    pa0.u[1] = hi ? xa3 : a1;
    pa0.u[2] = hi ? a2 : xa0;
    pa0.u[3] = hi ? a3 : xa1;
    pa1.u[0] = hi ? xb2 : b0;
    pa1.u[1] = hi ? xb3 : b1;
    pa1.u[2] = hi ? b2 : xb0;
    pa1.u[3] = hi ? b3 : xb1;

    // PV (O^T): acc[db] += Vt_frag[ks][db] * P_frag[ks]
    __builtin_amdgcn_s_setprio(1);
#pragma unroll
    for (int db = 0; db < 4; ++db) {
      acc[db] = __builtin_amdgcn_mfma_f32_32x32x16_bf16(vtf[0][db], pa0.v, acc[db], 0, 0, 0);
      acc[db] = __builtin_amdgcn_mfma_f32_32x32x16_bf16(vtf[1][db], pa1.v, acc[db], 0, 0, 0);
    }
    __builtin_amdgcn_s_setprio(0);
  }

  // epilogue: divide by l (lane-local) and store; d = db*32 + rq*8 + hi*4 + i
  float inv = 1.0f / lrow;
  u16* ob = AO + (size_t)(b * 2048 + q0 + ql) * 2048 + h * 128 + hi * 4;
#pragma unroll
  for (int db = 0; db < 4; ++db)
#pragma unroll
    for (int rq = 0; rq < 4; ++rq) {
      ushort4 o;
      o.x = f2b(acc[db][rq * 4 + 0] * inv);
      o.y = f2b(acc[db][rq * 4 + 1] * inv);
      o.z = f2b(acc[db][rq * 4 + 2] * inv);
      o.w = f2b(acc[db][rq * 4 + 3] * inv);
      *(ushort4*)(ob + db * 32 + rq * 8) = o;
    }
}

// ---------------- host ----------------
extern "C" void kernel_launch(void* const* d_in, const int* in_sizes, int n_in,
                              void* d_out, int out_size, void* d_ws, size_t ws_size,
                              hipStream_t stream) {
  const float* X = (const float*)d_in[0];
  const float* Wq = (const float*)d_in[1];
  const float* Wk = (const float*)d_in[2];
  const float* Wv = (const float*)d_in[3];
  const float* Wo = (const float*)d_in[4];

  u16* ws = (u16*)d_ws;
  const size_t nX = 8388608;   // 2*2048*2048
  const size_t nWq = 4194304;  // 2048*2048
  const size_t nWk = 1048576;  // 512*2048
  u16* Xb = ws;
  u16* Wqb = Xb + nX;
  u16* Wkb = Wqb + nWq;
  u16* Wvb = Wkb + nWk;
  u16* Wob = Wvb + nWk;
  u16* Qb = Wob + nWq;
  u16* Kb = Qb + nX;
  u16* Vtb = Kb + 2097152;
  u16* AOb = Vtb + 2097152;
  if (ws_size < (size_t)(39845888) * 2) return;

  cvt_bf16<<<8192, 256, 0, stream>>>(X, Xb, (int)nX);
  cvt_bf16<<<4096, 256, 0, stream>>>(Wq, Wqb, (int)nWq);
  cvt_bf16<<<1024, 256, 0, stream>>>(Wk, Wkb, (int)nWk);
  cvt_bf16<<<1024, 256, 0, stream>>>(Wv, Wvb, (int)nWk);
  cvt_bf16<<<4096, 256, 0, stream>>>(Wo, Wob, (int)nWq);

  gemm_bt<0><<<dim3(16, 32), 256, 0, stream>>>(Xb, Wqb, Qb, 4096, 2048, 2048);
  gemm_bt<0><<<dim3(4, 32), 256, 0, stream>>>(Xb, Wkb, Kb, 4096, 512, 2048);
  gemm_bt<1><<<dim3(4, 32), 256, 0, stream>>>(Xb, Wvb, Vtb, 4096, 512, 2048);

  attn_fwd<<<dim3(16, 32), 256, 0, stream>>>(Qb, Kb, Vtb, AOb);

  gemm_bt<2><<<dim3(16, 32), 256, 0, stream>>>(AOb, Wob, d_out, 4096, 2048, 2048);
}

// Round 6
// 277.552 us; speedup vs baseline: 2.9311x; 1.2685x over previous
//
#include <hip/hip_runtime.h>

typedef unsigned short u16;
typedef unsigned int u32;
typedef __attribute__((ext_vector_type(4))) float f32x4;
typedef __attribute__((ext_vector_type(16))) float f32x16;
typedef __attribute__((ext_vector_type(8))) short bf16x8;

// Problem sizes (fixed): B=2, S=2048, D=2048, NH=16, NKV=4, HD=128

__device__ __forceinline__ u16 f2b(float f) {
  u32 u = __builtin_bit_cast(u32, f);
  u = (u + 0x7fffu + ((u >> 16) & 1u)) >> 16;  // RNE
  return (u16)u;
}

__device__ __forceinline__ void gload_lds16(const void* g, void* l) {
  __builtin_amdgcn_global_load_lds((const __attribute__((address_space(1))) u32*)g,
                                   (__attribute__((address_space(3))) u32*)l, 16, 0, 0);
}

// ---------------- fp32 -> bf16 conversion ----------------
__global__ void cvt_bf16(const float* __restrict__ src, u16* __restrict__ dst, int n) {
  int stride = gridDim.x * blockDim.x * 4;
  for (int idx = (blockIdx.x * blockDim.x + threadIdx.x) * 4; idx < n; idx += stride) {
    float4 v = *(const float4*)(src + idx);
    ushort4 o;
    o.x = f2b(v.x); o.y = f2b(v.y); o.z = f2b(v.z); o.w = f2b(v.w);
    *(ushort4*)(dst + idx) = o;
  }
}

// fused weight conversion: dst = [Wq(4.19M) | Wk(1.05M) | Wv(1.05M) | Wo(4.19M)] contiguous
__global__ void cvt_w4(const float* __restrict__ Wq, const float* __restrict__ Wk,
                       const float* __restrict__ Wv, const float* __restrict__ Wo,
                       u16* __restrict__ dst) {
  const int total = 10485760;
  int stride = gridDim.x * blockDim.x * 4;
  for (int idx = (blockIdx.x * blockDim.x + threadIdx.x) * 4; idx < total; idx += stride) {
    const float* src;
    int off;
    if (idx < 4194304) { src = Wq; off = idx; }
    else if (idx < 5242880) { src = Wk; off = idx - 4194304; }
    else if (idx < 6291456) { src = Wv; off = idx - 5242880; }
    else { src = Wo; off = idx - 6291456; }
    float4 v = *(const float4*)(src + off);
    ushort4 o;
    o.x = f2b(v.x); o.y = f2b(v.y); o.z = f2b(v.z); o.w = f2b(v.w);
    *(ushort4*)(dst + idx) = o;
  }
}

// ---------------- GEMM: C[M,N] = A[M,K] * B[N,K]^T ----------------
// OUT_MODE: 0 = bf16 row-major; 2 = fp32 row-major; 3 = fused QKV routing
//   (col<2048 -> Q row-major ld=2048; col<2560 -> K row-major ld=512; else V^T)
template<int OUT_MODE>
__global__ __launch_bounds__(256) void gemm_bt(const u16* __restrict__ A, const u16* __restrict__ B,
                                               void* __restrict__ Cout, int M, int N, int Kd,
                                               u16* __restrict__ Kout, u16* __restrict__ Vtout) {
  __shared__ u16 sA[128 * 32];
  __shared__ u16 sB[128 * 32];
  const int tid = threadIdx.x;
  const int l = tid & 63, w = tid >> 6;
  const int wr = w >> 1, wc = w & 1;
  const int g = l >> 4, c = l & 15;
  const int tm = blockIdx.y * 128, tn = blockIdx.x * 128;

  f32x4 acc[4][4] = {};

  const int r0 = tid >> 2, cc = (tid & 3) << 3;

  for (int k0 = 0; k0 < Kd; k0 += 32) {
    __syncthreads();
    {
      const u16* srcA0 = A + (size_t)(tm + r0) * Kd + k0 + cc;
      const u16* srcB0 = B + (size_t)(tn + r0) * Kd + k0 + cc;
      gload_lds16(srcA0, (char*)sA + w * 1024);
      gload_lds16(srcB0, (char*)sB + w * 1024);
      gload_lds16(srcA0 + (size_t)64 * Kd, (char*)sA + 4096 + w * 1024);
      gload_lds16(srcB0 + (size_t)64 * Kd, (char*)sB + 4096 + w * 1024);
    }
    __syncthreads();

    bf16x8 af[4], bfr[4];
#pragma unroll
    for (int m = 0; m < 4; ++m)
      af[m] = *(const bf16x8*)(sA + (wr * 64 + m * 16 + c) * 32 + g * 8);
#pragma unroll
    for (int n = 0; n < 4; ++n)
      bfr[n] = *(const bf16x8*)(sB + (wc * 64 + n * 16 + c) * 32 + g * 8);
#pragma unroll
    for (int m = 0; m < 4; ++m)
#pragma unroll
      for (int n = 0; n < 4; ++n)
        acc[m][n] = __builtin_amdgcn_mfma_f32_16x16x32_bf16(af[m], bfr[n], acc[m][n], 0, 0, 0);
  }

#pragma unroll
  for (int m = 0; m < 4; ++m)
#pragma unroll
    for (int n = 0; n < 4; ++n)
#pragma unroll
      for (int i = 0; i < 4; ++i) {
        int row = tm + wr * 64 + m * 16 + g * 4 + i;
        int col = tn + wc * 64 + n * 16 + c;
        float v = acc[m][n][i];
        if constexpr (OUT_MODE == 2) {
          ((float*)Cout)[(size_t)row * N + col] = v;
        } else if constexpr (OUT_MODE == 0) {
          ((u16*)Cout)[(size_t)row * N + col] = f2b(v);
        } else {
          if (tn < 2048) {
            ((u16*)Cout)[(size_t)row * 2048 + col] = f2b(v);          // Q
          } else if (tn < 2560) {
            Kout[(size_t)row * 512 + (col - 2048)] = f2b(v);          // K
          } else {
            int bb = row >> 11, s = row & 2047;                        // V^T
            Vtout[((size_t)bb * 512 + (col - 2560)) * 2048 + s] = f2b(v);
          }
        }
      }
}

// ---------------- causal GQA flash attention: 32x32 swapped-operand, register-resident -------
// grid (16, B*NH), block 256 (4 waves). Waves 0,1 -> 64-row tile x; waves 2,3 -> tile 31-x.
// Lane owns q = q0 + (lane&31) throughout; softmax state m,l lane-local.
// K fragments double-buffered one tile ahead (hides VMEM latency under softmax+PV of prev tile).
__global__ __launch_bounds__(256, 2) void attn_fwd(const u16* __restrict__ Q, const u16* __restrict__ Kt,
                                                   const u16* __restrict__ Vt, u16* __restrict__ AO) {
  const int l = threadIdx.x & 63, w = threadIdx.x >> 6;
  const int ql = l & 31, hi = l >> 5;
  const int bh = blockIdx.y;
  const int b = bh >> 4, h = bh & 15;
  const int kvh = h >> 2;

  const float sm = 0.08838834764831845f * 1.4426950408889634f;  // 1/sqrt(128) * log2(e)

  const u16* Kb = Kt + (size_t)(b * 2048) * 512 + kvh * 128;
  const u16* Vb = Vt + (size_t)(b * 512 + kvh * 128) * 2048;

  const int tile = (w < 2) ? blockIdx.x : (31 - blockIdx.x);
  const int q0 = tile * 64 + (w & 1) * 32;

  // Q fragments (B-operand of QK: col=q=lane&31, k = ck*16 + hi*8 + j)
  bf16x8 qf[8];
  {
    const u16* qb = Q + ((size_t)(b * 2048 + q0 + ql)) * 2048 + h * 128 + hi * 8;
#pragma unroll
    for (int ck = 0; ck < 8; ++ck) qf[ck] = *(const bf16x8*)(qb + ck * 16);
  }

  f32x16 acc[4] = {};  // O^T[d = db*32 + crow(r)][q = q0 + (lane&31)]
  float mrow = -1e30f, lrow = 0.f;

  bf16x8 kfa[8], kfb[8];

#define LOADK(KF, KV0)                                                        \
  do {                                                                        \
    const u16* kb_ = Kb + (size_t)((KV0) + ql) * 512 + hi * 8;                \
    _Pragma("unroll") for (int ck = 0; ck < 8; ++ck)                          \
        KF[ck] = *(const bf16x8*)(kb_ + ck * 16);                             \
  } while (0)

#define COMPUTE(KF, KV0)                                                      \
  do {                                                                        \
    /* V^T fragments for THIS tile (A-operand of PV): latency hides under QK+softmax */ \
    bf16x8 vtf[2][4];                                                         \
    {                                                                         \
      const u16* vb_ = Vb + (size_t)ql * 2048 + (KV0) + hi * 8;               \
      _Pragma("unroll") for (int ks = 0; ks < 2; ++ks)                        \
      _Pragma("unroll") for (int db = 0; db < 4; ++db)                        \
          vtf[ks][db] = *(const bf16x8*)(vb_ + (size_t)(db * 32) * 2048 + ks * 16); \
    }                                                                         \
    f32x16 sacc = {};                                                         \
    __builtin_amdgcn_s_setprio(1);                                            \
    _Pragma("unroll") for (int ck = 0; ck < 8; ++ck)                          \
        sacc = __builtin_amdgcn_mfma_f32_32x32x16_bf16(KF[ck], qf[ck], sacc, 0, 0, 0); \
    __builtin_amdgcn_s_setprio(0);                                            \
    if ((KV0) == q0) { /* diagonal: mask kv > q */                            \
      _Pragma("unroll") for (int r = 0; r < 16; ++r) {                        \
        int crow = (r & 3) + 8 * (r >> 2) + 4 * hi;                           \
        if (crow > ql) sacc[r] = -1e30f;                                      \
      }                                                                       \
    }                                                                         \
    float mx = sacc[0];                                                       \
    _Pragma("unroll") for (int r = 1; r < 16; ++r) mx = fmaxf(mx, sacc[r]);   \
    mx = fmaxf(mx, __shfl_xor(mx, 32));                                       \
    if (!__all((mx - mrow) * sm <= 8.0f)) { /* T13 defer-max */               \
      float mnew = fmaxf(mrow, mx);                                           \
      float rs = exp2f((mrow - mnew) * sm);                                   \
      mrow = mnew;                                                            \
      lrow *= rs;                                                             \
      _Pragma("unroll") for (int db = 0; db < 4; ++db)                        \
      _Pragma("unroll") for (int r = 0; r < 16; ++r) acc[db][r] *= rs;        \
    }                                                                         \
    float p[16];                                                              \
    float psum = 0.f;                                                         \
    _Pragma("unroll") for (int r = 0; r < 16; ++r) {                          \
      p[r] = exp2f((sacc[r] - mrow) * sm);                                    \
      psum += p[r];                                                           \
    }                                                                         \
    psum += __shfl_xor(psum, 32);                                             \
    lrow += psum;                                                             \
    u32 a0 = (u32)f2b(p[0]) | ((u32)f2b(p[1]) << 16);                         \
    u32 a1 = (u32)f2b(p[2]) | ((u32)f2b(p[3]) << 16);                         \
    u32 a2 = (u32)f2b(p[4]) | ((u32)f2b(p[5]) << 16);                         \
    u32 a3 = (u32)f2b(p[6]) | ((u32)f2b(p[7]) << 16);                         \
    u32 b0 = (u32)f2b(p[8]) | ((u32)f2b(p[9]) << 16);                         \
    u32 b1 = (u32)f2b(p[10]) | ((u32)f2b(p[11]) << 16);                       \
    u32 b2 = (u32)f2b(p[12]) | ((u32)f2b(p[13]) << 16);                       \
    u32 b3 = (u32)f2b(p[14]) | ((u32)f2b(p[15]) << 16);                       \
    u32 xa0 = (u32)__shfl_xor((int)a0, 32), xa1 = (u32)__shfl_xor((int)a1, 32); \
    u32 xa2 = (u32)__shfl_xor((int)a2, 32), xa3 = (u32)__shfl_xor((int)a3, 32); \
    u32 xb0 = (u32)__shfl_xor((int)b0, 32), xb1 = (u32)__shfl_xor((int)b1, 32); \
    u32 xb2 = (u32)__shfl_xor((int)b2, 32), xb3 = (u32)__shfl_xor((int)b3, 32); \
    union { bf16x8 v; u32 u[4]; } pa0, pa1;                                   \
    pa0.u[0] = hi ? xa2 : a0;                                                 \
    pa0.u[1] = hi ? xa3 : a1;                                                 \
    pa0.u[2] = hi ? a2 : xa0;                                                 \
    pa0.u[3] = hi ? a3 : xa1;                                                 \
    pa1.u[0] = hi ? xb2 : b0;                                                 \
    pa1.u[1] = hi ? xb3 : b1;                                                 \
    pa1.u[2] = hi ? b2 : xb0;                                                 \
    pa1.u[3] = hi ? b3 : xb1;                                                 \
    __builtin_amdgcn_s_setprio(1);                                            \
    _Pragma("unroll") for (int db = 0; db < 4; ++db) {                        \
      acc[db] = __builtin_amdgcn_mfma_f32_32x32x16_bf16(vtf[0][db], pa0.v, acc[db], 0, 0, 0); \
      acc[db] = __builtin_amdgcn_mfma_f32_32x32x16_bf16(vtf[1][db], pa1.v, acc[db], 0, 0, 0); \
    }                                                                         \
    __builtin_amdgcn_s_setprio(0);                                            \
  } while (0)

  LOADK(kfa, 0);
  int kv0 = 0;
  while (true) {
    bool more = kv0 < q0;
    if (more) LOADK(kfb, kv0 + 32);
    COMPUTE(kfa, kv0);
    if (!more) break;
    kv0 += 32;
    more = kv0 < q0;
    if (more) LOADK(kfa, kv0 + 32);
    COMPUTE(kfb, kv0);
    if (!more) break;
    kv0 += 32;
  }
#undef LOADK
#undef COMPUTE

  // epilogue: divide by l (lane-local) and store; d = db*32 + rq*8 + hi*4 + i
  float inv = 1.0f / lrow;
  u16* ob = AO + (size_t)(b * 2048 + q0 + ql) * 2048 + h * 128 + hi * 4;
#pragma unroll
  for (int db = 0; db < 4; ++db)
#pragma unroll
    for (int rq = 0; rq < 4; ++rq) {
      ushort4 o;
      o.x = f2b(acc[db][rq * 4 + 0] * inv);
      o.y = f2b(acc[db][rq * 4 + 1] * inv);
      o.z = f2b(acc[db][rq * 4 + 2] * inv);
      o.w = f2b(acc[db][rq * 4 + 3] * inv);
      *(ushort4*)(ob + db * 32 + rq * 8) = o;
    }
}

// ---------------- host ----------------
extern "C" void kernel_launch(void* const* d_in, const int* in_sizes, int n_in,
                              void* d_out, int out_size, void* d_ws, size_t ws_size,
                              hipStream_t stream) {
  const float* X = (const float*)d_in[0];
  const float* Wq = (const float*)d_in[1];
  const float* Wk = (const float*)d_in[2];
  const float* Wv = (const float*)d_in[3];
  const float* Wo = (const float*)d_in[4];

  u16* ws = (u16*)d_ws;
  const size_t nX = 8388608;   // 2*2048*2048
  const size_t nWq = 4194304;  // 2048*2048
  const size_t nWk = 1048576;  // 512*2048
  u16* Xb = ws;
  u16* Wqb = Xb + nX;          // [Wq|Wk|Wv] contiguous = fused 3072x2048 weight
  u16* Wkb = Wqb + nWq;
  u16* Wvb = Wkb + nWk;
  u16* Wob = Wvb + nWk;
  u16* Qb = Wob + nWq;
  u16* Kb = Qb + nX;
  u16* Vtb = Kb + 2097152;
  u16* AOb = Vtb + 2097152;
  if (ws_size < (size_t)(39845888) * 2) return;

  cvt_bf16<<<2048, 256, 0, stream>>>(X, Xb, (int)nX);
  cvt_w4<<<2048, 256, 0, stream>>>(Wq, Wk, Wv, Wo, Wqb);

  // fused QKV projection: C[4096][3072] routed to Q / K / V^T
  gemm_bt<3><<<dim3(24, 32), 256, 0, stream>>>(Xb, Wqb, Qb, 4096, 3072, 2048, Kb, Vtb);

  attn_fwd<<<dim3(16, 32), 256, 0, stream>>>(Qb, Kb, Vtb, AOb);

  // output projection -> fp32 d_out
  gemm_bt<2><<<dim3(16, 32), 256, 0, stream>>>(AOb, Wob, d_out, 4096, 2048, 2048, nullptr, nullptr);
}

// Round 7
// 276.055 us; speedup vs baseline: 2.9470x; 1.0054x over previous
//
#include <hip/hip_runtime.h>

typedef unsigned short u16;
typedef unsigned int u32;
typedef __attribute__((ext_vector_type(4))) float f32x4;
typedef __attribute__((ext_vector_type(16))) float f32x16;
typedef __attribute__((ext_vector_type(8))) short bf16x8;

// Problem sizes (fixed): B=2, S=2048, D=2048, NH=16, NKV=4, HD=128

__device__ __forceinline__ u16 f2b(float f) {
  u32 u = __builtin_bit_cast(u32, f);
  u = (u + 0x7fffu + ((u >> 16) & 1u)) >> 16;  // RNE
  return (u16)u;
}

__device__ __forceinline__ void gload_lds16(const void* g, void* l) {
  __builtin_amdgcn_global_load_lds((const __attribute__((address_space(1))) u32*)g,
                                   (__attribute__((address_space(3))) u32*)l, 16, 0, 0);
}

// ---- cross-half (lane <-> lane^32) exchange via v_permlane32_swap_b32 (VALU pipe, not LDS) ----
// swap(x,y): rx = [x.lo | y.lo], ry = [x.hi | y.hi]  (lane i>=32 of rx gets y[i-32]; lane i<32
// of ry gets x[i+32]).  Builtin is SSA-safe (round-4's inline-asm "+v" aliasing caused NaN).
#if __has_builtin(__builtin_amdgcn_permlane32_swap)
#define HAS_PLS 1
__device__ __forceinline__ void pls(u32 x, u32 y, u32& rx, u32& ry) {
  auto r = __builtin_amdgcn_permlane32_swap(x, y, false, false);
  rx = (u32)r[0];
  ry = (u32)r[1];
}
#endif

__device__ __forceinline__ float xhalf_max(float v) {
#ifdef HAS_PLS
  u32 a, b;
  pls(__builtin_bit_cast(u32, v), __builtin_bit_cast(u32, v), a, b);
  return fmaxf(__builtin_bit_cast(float, a), __builtin_bit_cast(float, b));
#else
  return fmaxf(v, __shfl_xor(v, 32));
#endif
}

__device__ __forceinline__ float xhalf_sum(float v) {
#ifdef HAS_PLS
  u32 a, b;
  pls(__builtin_bit_cast(u32, v), __builtin_bit_cast(u32, v), a, b);
  return __builtin_bit_cast(float, a) + __builtin_bit_cast(float, b);
#else
  return v + __shfl_xor(v, 32);
#endif
}

// P-fragment redistribution: lane needs [own lo-words | partner words] per slot pattern
// lo lane: [a0, a1, Xa0, Xa1]; hi lane: [Xa2, Xa3, a2, a3]  (X = partner lane^32)
__device__ __forceinline__ void xexchange(int hi, u32 a0, u32 a1, u32 a2, u32 a3, u32* o) {
#ifdef HAS_PLS
  pls(a0, a2, o[0], o[2]);
  pls(a1, a3, o[1], o[3]);
#else
  u32 xa0 = (u32)__shfl_xor((int)a0, 32), xa1 = (u32)__shfl_xor((int)a1, 32);
  u32 xa2 = (u32)__shfl_xor((int)a2, 32), xa3 = (u32)__shfl_xor((int)a3, 32);
  o[0] = hi ? xa2 : a0;
  o[1] = hi ? xa3 : a1;
  o[2] = hi ? a2 : xa0;
  o[3] = hi ? a3 : xa1;
#endif
}

// ---------------- fp32 -> bf16 conversion ----------------
__global__ void cvt_bf16(const float* __restrict__ src, u16* __restrict__ dst, int n) {
  int stride = gridDim.x * blockDim.x * 4;
  for (int idx = (blockIdx.x * blockDim.x + threadIdx.x) * 4; idx < n; idx += stride) {
    float4 v = *(const float4*)(src + idx);
    ushort4 o;
    o.x = f2b(v.x); o.y = f2b(v.y); o.z = f2b(v.z); o.w = f2b(v.w);
    *(ushort4*)(dst + idx) = o;
  }
}

// fused weight conversion: dst = [Wq(4.19M) | Wk(1.05M) | Wv(1.05M) | Wo(4.19M)] contiguous
__global__ void cvt_w4(const float* __restrict__ Wq, const float* __restrict__ Wk,
                       const float* __restrict__ Wv, const float* __restrict__ Wo,
                       u16* __restrict__ dst) {
  const int total = 10485760;
  int stride = gridDim.x * blockDim.x * 4;
  for (int idx = (blockIdx.x * blockDim.x + threadIdx.x) * 4; idx < total; idx += stride) {
    const float* src;
    int off;
    if (idx < 4194304) { src = Wq; off = idx; }
    else if (idx < 5242880) { src = Wk; off = idx - 4194304; }
    else if (idx < 6291456) { src = Wv; off = idx - 5242880; }
    else { src = Wo; off = idx - 6291456; }
    float4 v = *(const float4*)(src + off);
    ushort4 o;
    o.x = f2b(v.x); o.y = f2b(v.y); o.z = f2b(v.z); o.w = f2b(v.w);
    *(ushort4*)(dst + idx) = o;
  }
}

// ---------------- GEMM: C[M,N] = A[M,K] * B[N,K]^T ----------------
// OUT_MODE: 0 = bf16 row-major; 2 = fp32 row-major; 3 = fused QKV routing
template<int OUT_MODE>
__global__ __launch_bounds__(256) void gemm_bt(const u16* __restrict__ A, const u16* __restrict__ B,
                                               void* __restrict__ Cout, int M, int N, int Kd,
                                               u16* __restrict__ Kout, u16* __restrict__ Vtout) {
  __shared__ u16 sA[128 * 32];
  __shared__ u16 sB[128 * 32];
  const int tid = threadIdx.x;
  const int l = tid & 63, w = tid >> 6;
  const int wr = w >> 1, wc = w & 1;
  const int g = l >> 4, c = l & 15;
  const int tm = blockIdx.y * 128, tn = blockIdx.x * 128;

  f32x4 acc[4][4] = {};

  const int r0 = tid >> 2, cc = (tid & 3) << 3;

  for (int k0 = 0; k0 < Kd; k0 += 32) {
    __syncthreads();
    {
      const u16* srcA0 = A + (size_t)(tm + r0) * Kd + k0 + cc;
      const u16* srcB0 = B + (size_t)(tn + r0) * Kd + k0 + cc;
      gload_lds16(srcA0, (char*)sA + w * 1024);
      gload_lds16(srcB0, (char*)sB + w * 1024);
      gload_lds16(srcA0 + (size_t)64 * Kd, (char*)sA + 4096 + w * 1024);
      gload_lds16(srcB0 + (size_t)64 * Kd, (char*)sB + 4096 + w * 1024);
    }
    __syncthreads();

    bf16x8 af[4], bfr[4];
#pragma unroll
    for (int m = 0; m < 4; ++m)
      af[m] = *(const bf16x8*)(sA + (wr * 64 + m * 16 + c) * 32 + g * 8);
#pragma unroll
    for (int n = 0; n < 4; ++n)
      bfr[n] = *(const bf16x8*)(sB + (wc * 64 + n * 16 + c) * 32 + g * 8);
#pragma unroll
    for (int m = 0; m < 4; ++m)
#pragma unroll
      for (int n = 0; n < 4; ++n)
        acc[m][n] = __builtin_amdgcn_mfma_f32_16x16x32_bf16(af[m], bfr[n], acc[m][n], 0, 0, 0);
  }

#pragma unroll
  for (int m = 0; m < 4; ++m)
#pragma unroll
    for (int n = 0; n < 4; ++n)
#pragma unroll
      for (int i = 0; i < 4; ++i) {
        int row = tm + wr * 64 + m * 16 + g * 4 + i;
        int col = tn + wc * 64 + n * 16 + c;
        float v = acc[m][n][i];
        if constexpr (OUT_MODE == 2) {
          ((float*)Cout)[(size_t)row * N + col] = v;
        } else if constexpr (OUT_MODE == 0) {
          ((u16*)Cout)[(size_t)row * N + col] = f2b(v);
        } else {
          if (tn < 2048) {
            ((u16*)Cout)[(size_t)row * 2048 + col] = f2b(v);          // Q
          } else if (tn < 2560) {
            Kout[(size_t)row * 512 + (col - 2048)] = f2b(v);          // K
          } else {
            int bb = row >> 11, s = row & 2047;                        // V^T
            Vtout[((size_t)bb * 512 + (col - 2560)) * 2048 + s] = f2b(v);
          }
        }
      }
}

// ---------------- causal GQA flash attention: 32x32 swapped-operand, register-resident -------
// grid (16, B*NH), block 256 (4 waves). Waves 0,1 -> 64-row tile x; waves 2,3 -> tile 31-x.
// Lane owns q = q0 + (lane&31); softmax state m,l lane-local. Cross-lane traffic per tile:
// 6 v_permlane32_swap (VALU pipe) — zero LDS-pipe ops (bpermute-free).
__global__ __launch_bounds__(256, 2) void attn_fwd(const u16* __restrict__ Q, const u16* __restrict__ Kt,
                                                   const u16* __restrict__ Vt, u16* __restrict__ AO) {
  const int l = threadIdx.x & 63, w = threadIdx.x >> 6;
  const int ql = l & 31, hi = l >> 5;
  const int bh = blockIdx.y;
  const int b = bh >> 4, h = bh & 15;
  const int kvh = h >> 2;

  const float sm = 0.08838834764831845f * 1.4426950408889634f;  // 1/sqrt(128) * log2(e)

  const u16* Kb = Kt + (size_t)(b * 2048) * 512 + kvh * 128;
  const u16* Vb = Vt + (size_t)(b * 512 + kvh * 128) * 2048;

  const int tile = (w < 2) ? blockIdx.x : (31 - blockIdx.x);
  const int q0 = tile * 64 + (w & 1) * 32;

  // Q fragments (B-operand of QK: col=q=lane&31, k = ck*16 + hi*8 + j)
  bf16x8 qf[8];
  {
    const u16* qb = Q + ((size_t)(b * 2048 + q0 + ql)) * 2048 + h * 128 + hi * 8;
#pragma unroll
    for (int ck = 0; ck < 8; ++ck) qf[ck] = *(const bf16x8*)(qb + ck * 16);
  }

  f32x16 acc[4] = {};  // O^T[d = db*32 + crow(r)][q = q0 + (lane&31)]
  float mrow = -1e30f, lrow = 0.f;

  bf16x8 kfa[8], kfb[8];

#define LOADK(KF, KV0)                                                        \
  do {                                                                        \
    const u16* kb_ = Kb + (size_t)((KV0) + ql) * 512 + hi * 8;                \
    _Pragma("unroll") for (int ck = 0; ck < 8; ++ck)                          \
        KF[ck] = *(const bf16x8*)(kb_ + ck * 16);                             \
  } while (0)

#define COMPUTE(KF, KV0)                                                      \
  do {                                                                        \
    /* V^T fragments for THIS tile (A-operand of PV) */                       \
    bf16x8 vtf[2][4];                                                         \
    {                                                                         \
      const u16* vb_ = Vb + (size_t)ql * 2048 + (KV0) + hi * 8;               \
      _Pragma("unroll") for (int ks = 0; ks < 2; ++ks)                        \
      _Pragma("unroll") for (int db = 0; db < 4; ++db)                        \
          vtf[ks][db] = *(const bf16x8*)(vb_ + (size_t)(db * 32) * 2048 + ks * 16); \
    }                                                                         \
    f32x16 sacc = {};                                                         \
    __builtin_amdgcn_s_setprio(1);                                            \
    _Pragma("unroll") for (int ck = 0; ck < 8; ++ck)                          \
        sacc = __builtin_amdgcn_mfma_f32_32x32x16_bf16(KF[ck], qf[ck], sacc, 0, 0, 0); \
    __builtin_amdgcn_s_setprio(0);                                            \
    if ((KV0) == q0) { /* diagonal: mask kv > q */                            \
      _Pragma("unroll") for (int r = 0; r < 16; ++r) {                        \
        int crow = (r & 3) + 8 * (r >> 2) + 4 * hi;                           \
        if (crow > ql) sacc[r] = -1e30f;                                      \
      }                                                                       \
    }                                                                         \
    /* tree max (4 levels) */                                                 \
    float t0 = fmaxf(sacc[0], sacc[1]), t1 = fmaxf(sacc[2], sacc[3]);         \
    float t2 = fmaxf(sacc[4], sacc[5]), t3 = fmaxf(sacc[6], sacc[7]);         \
    float t4 = fmaxf(sacc[8], sacc[9]), t5 = fmaxf(sacc[10], sacc[11]);       \
    float t6 = fmaxf(sacc[12], sacc[13]), t7 = fmaxf(sacc[14], sacc[15]);     \
    float mx = fmaxf(fmaxf(fmaxf(t0, t1), fmaxf(t2, t3)),                     \
                     fmaxf(fmaxf(t4, t5), fmaxf(t6, t7)));                    \
    mx = xhalf_max(mx);                                                       \
    /* speculative P with current mrow (issues alongside the max tree) */     \
    float p[16];                                                              \
    _Pragma("unroll") for (int r = 0; r < 16; ++r)                            \
        p[r] = exp2f((sacc[r] - mrow) * sm);                                  \
    if (!__all((mx - mrow) * sm <= 8.0f)) { /* T13 defer-max: rare rescale */ \
      float mnew = fmaxf(mrow, mx);                                           \
      float rs = exp2f((mrow - mnew) * sm);                                   \
      mrow = mnew;                                                            \
      lrow *= rs;                                                             \
      _Pragma("unroll") for (int db = 0; db < 4; ++db)                        \
      _Pragma("unroll") for (int r = 0; r < 16; ++r) acc[db][r] *= rs;        \
      _Pragma("unroll") for (int r = 0; r < 16; ++r)                          \
          p[r] = exp2f((sacc[r] - mrow) * sm);                                \
    }                                                                         \
    /* tree sum */                                                            \
    float s0 = p[0] + p[1], s1 = p[2] + p[3], s2 = p[4] + p[5], s3 = p[6] + p[7]; \
    float s4 = p[8] + p[9], s5 = p[10] + p[11], s6 = p[12] + p[13], s7 = p[14] + p[15]; \
    float psum = ((s0 + s1) + (s2 + s3)) + ((s4 + s5) + (s6 + s7));           \
    lrow += xhalf_sum(psum);                                                  \
    /* pack P pairs */                                                        \
    u32 a0 = (u32)f2b(p[0]) | ((u32)f2b(p[1]) << 16);                         \
    u32 a1 = (u32)f2b(p[2]) | ((u32)f2b(p[3]) << 16);                         \
    u32 a2 = (u32)f2b(p[4]) | ((u32)f2b(p[5]) << 16);                         \
    u32 a3 = (u32)f2b(p[6]) | ((u32)f2b(p[7]) << 16);                         \
    u32 b0 = (u32)f2b(p[8]) | ((u32)f2b(p[9]) << 16);                         \
    u32 b1 = (u32)f2b(p[10]) | ((u32)f2b(p[11]) << 16);                       \
    u32 b2 = (u32)f2b(p[12]) | ((u32)f2b(p[13]) << 16);                       \
    u32 b3 = (u32)f2b(p[14]) | ((u32)f2b(p[15]) << 16);                       \
    union { bf16x8 v; u32 u[4]; } pa0, pa1;                                   \
    xexchange(hi, a0, a1, a2, a3, pa0.u);                                     \
    xexchange(hi, b0, b1, b2, b3, pa1.u);                                     \
    __builtin_amdgcn_s_setprio(1);                                            \
    _Pragma("unroll") for (int db = 0; db < 4; ++db) {                        \
      acc[db] = __builtin_amdgcn_mfma_f32_32x32x16_bf16(vtf[0][db], pa0.v, acc[db], 0, 0, 0); \
      acc[db] = __builtin_amdgcn_mfma_f32_32x32x16_bf16(vtf[1][db], pa1.v, acc[db], 0, 0, 0); \
    }                                                                         \
    __builtin_amdgcn_s_setprio(0);                                            \
  } while (0)

  LOADK(kfa, 0);
  int kv0 = 0;
  while (true) {
    bool more = kv0 < q0;
    if (more) LOADK(kfb, kv0 + 32);
    COMPUTE(kfa, kv0);
    if (!more) break;
    kv0 += 32;
    more = kv0 < q0;
    if (more) LOADK(kfa, kv0 + 32);
    COMPUTE(kfb, kv0);
    if (!more) break;
    kv0 += 32;
  }
#undef LOADK
#undef COMPUTE

  // epilogue: divide by l (lane-local) and store; d = db*32 + rq*8 + hi*4 + i
  float inv = 1.0f / lrow;
  u16* ob = AO + (size_t)(b * 2048 + q0 + ql) * 2048 + h * 128 + hi * 4;
#pragma unroll
  for (int db = 0; db < 4; ++db)
#pragma unroll
    for (int rq = 0; rq < 4; ++rq) {
      ushort4 o;
      o.x = f2b(acc[db][rq * 4 + 0] * inv);
      o.y = f2b(acc[db][rq * 4 + 1] * inv);
      o.z = f2b(acc[db][rq * 4 + 2] * inv);
      o.w = f2b(acc[db][rq * 4 + 3] * inv);
      *(ushort4*)(ob + db * 32 + rq * 8) = o;
    }
}

// ---------------- host ----------------
extern "C" void kernel_launch(void* const* d_in, const int* in_sizes, int n_in,
                              void* d_out, int out_size, void* d_ws, size_t ws_size,
                              hipStream_t stream) {
  const float* X = (const float*)d_in[0];
  const float* Wq = (const float*)d_in[1];
  const float* Wk = (const float*)d_in[2];
  const float* Wv = (const float*)d_in[3];
  const float* Wo = (const float*)d_in[4];

  u16* ws = (u16*)d_ws;
  const size_t nX = 8388608;   // 2*2048*2048
  const size_t nWq = 4194304;  // 2048*2048
  const size_t nWk = 1048576;  // 512*2048
  u16* Xb = ws;
  u16* Wqb = Xb + nX;          // [Wq|Wk|Wv] contiguous = fused 3072x2048 weight
  u16* Wkb = Wqb + nWq;
  u16* Wvb = Wkb + nWk;
  u16* Wob = Wvb + nWk;
  u16* Qb = Wob + nWq;
  u16* Kb = Qb + nX;
  u16* Vtb = Kb + 2097152;
  u16* AOb = Vtb + 2097152;
  if (ws_size < (size_t)(39845888) * 2) return;

  cvt_bf16<<<2048, 256, 0, stream>>>(X, Xb, (int)nX);
  cvt_w4<<<2048, 256, 0, stream>>>(Wq, Wk, Wv, Wo, Wqb);

  // fused QKV projection: C[4096][3072] routed to Q / K / V^T
  gemm_bt<3><<<dim3(24, 32), 256, 0, stream>>>(Xb, Wqb, Qb, 4096, 3072, 2048, Kb, Vtb);

  attn_fwd<<<dim3(16, 32), 256, 0, stream>>>(Qb, Kb, Vtb, AOb);

  // output projection -> fp32 d_out
  gemm_bt<2><<<dim3(16, 32), 256, 0, stream>>>(AOb, Wob, d_out, 4096, 2048, 2048, nullptr, nullptr);
}